// Round 7
// baseline (220.222 us; speedup 1.0000x reference)
//
#include <hip/hip_runtime.h>

// MaskedAttentionLayer B=4,S=2048,E=1024,H=16,HD=64; fp32 io, bf16 MFMA.
// R7: (a) qkv_gemm __launch_bounds__(256,3): cap V+A so 3 blocks/CU resident
// (was 184/wave -> 2 blocks/CU, barrier drains uncovered).
// (b) flash_attn: 64-row q-tiles, grid 1024 (R5 residency) but KT=128 staged
// per barrier pair (two 64-k subtiles per stage -> 36 MFMA/wave per pair).
// Triangle pairing uniform: stages(31-p)+stages(p)=17 for all p.

typedef __bf16 bf16x8 __attribute__((ext_vector_type(8)));
typedef __bf16 bf16x4 __attribute__((ext_vector_type(4)));
typedef float f32x4 __attribute__((ext_vector_type(4)));
typedef unsigned short us8 __attribute__((ext_vector_type(8)));
typedef unsigned short us4 __attribute__((ext_vector_type(4)));

#define Bb 4
#define Ss 2048
#define Ee 1024
#define Hh 16
#define HD 64

#if __has_builtin(__builtin_amdgcn_exp2f)
#define EXP2(x) __builtin_amdgcn_exp2f(x)
#else
#define EXP2(x) exp2f(x)
#endif

__device__ __forceinline__ unsigned short f2bf(float f) {
  union { float f; unsigned u; } v; v.f = f;
  unsigned u = v.u;
  u += 0x7fffu + ((u >> 16) & 1u);   // RNE
  return (unsigned short)(u >> 16);
}

__device__ __forceinline__ void gl_lds16(const void* g, void* l) {
  __builtin_amdgcn_global_load_lds((const __attribute__((address_space(1))) void*)g,
                                   (__attribute__((address_space(3))) void*)l, 16, 0, 0);
}

// one kernel for all fp32->bf16 converts (x, Wq, Wk, Wv)
__global__ __launch_bounds__(256) void cvt_all(const float* __restrict__ x,
                                               const float* __restrict__ wq,
                                               const float* __restrict__ wk,
                                               const float* __restrict__ wv,
                                               unsigned short* __restrict__ xb,
                                               unsigned short* __restrict__ wb) {
  int i = blockIdx.x * 256 + threadIdx.x;   // float4 index, total 2883584
  const float* src; unsigned short* dst; int idx;
  if (i < 2097152)      { src = x;  dst = xb;                idx = i; }
  else if (i < 2359296) { src = wq; dst = wb;                idx = i - 2097152; }
  else if (i < 2621440) { src = wk; dst = wb + 1048576;      idx = i - 2359296; }
  else                  { src = wv; dst = wb + 2 * 1048576;  idx = i - 2621440; }
  float4 f = ((const float4*)src)[idx];
  us4 o = { f2bf(f.x), f2bf(f.y), f2bf(f.z), f2bf(f.w) };
  ((us4*)dst)[idx] = o;
}

// C[m,n] = sum_e X[m,e] W[n,e] + bias[n].  128x128 tile, BK=64 (2x32 panels).
// __launch_bounds__(256,3): target 3 blocks/CU (V+A <= ~168).
// z=0 (Q): [b,h,s,d] scaled by 0.125*log2e.  z=1 (K): [b,h,s,d].  z=2 (V): [b,h,d,s].
__global__ __launch_bounds__(256, 3) void qkv_gemm(const unsigned short* __restrict__ xb,
                                                   const unsigned short* __restrict__ wb_all,
                                                   const float* __restrict__ bq,
                                                   const float* __restrict__ bk,
                                                   const float* __restrict__ bv,
                                                   unsigned short* __restrict__ qkv) {
  const int z = blockIdx.z;
  const unsigned short* wb = wb_all + (size_t)z * (Ee * Ee);
  const float* bias = (z == 0) ? bq : (z == 1) ? bk : bv;
  unsigned short* outb = qkv + (size_t)z * (Bb * Ss * Ee);
  const float osc = (z == 0) ? 0.180336880f : 1.0f;   // 0.125 * log2(e)

  __shared__ unsigned short SMEM[16384];
  unsigned short* As = SMEM;
  unsigned short* Bs = SMEM + 8192;

  const int t = threadIdx.x;
  const int wave = t >> 6, lane = t & 63, quad = lane >> 4, ln = lane & 15;
  const int wm = wave & 1, wn = wave >> 1;
  const int m0 = blockIdx.x * 128, n0 = blockIdx.y * 128;

  const int srow = t >> 2;
  const int scol = (t & 3) * 8;

  f32x4 acc[4][4] = {};

  const unsigned short* ga = xb + (size_t)(m0 + srow) * Ee + scol;
  const unsigned short* gb = wb + (size_t)(n0 + srow) * Ee + scol;
  unsigned short* la = &As[t * 8];
  unsigned short* lb = &Bs[t * 8];

  for (int k0 = 0; k0 < Ee; k0 += 64) {
    __syncthreads();
    gl_lds16(ga + k0,                la);
    gl_lds16(ga + k0 + 64 * Ee,      la + 64 * 32);
    gl_lds16(gb + k0,                lb);
    gl_lds16(gb + k0 + 64 * Ee,      lb + 64 * 32);
    gl_lds16(ga + k0 + 32,           la + 4096);
    gl_lds16(ga + k0 + 32 + 64 * Ee, la + 4096 + 64 * 32);
    gl_lds16(gb + k0 + 32,           lb + 4096);
    gl_lds16(gb + k0 + 32 + 64 * Ee, lb + 4096 + 64 * 32);
    __syncthreads();
#pragma unroll
    for (int p = 0; p < 2; ++p) {
      bf16x8 af[4], bfr[4];
#pragma unroll
      for (int i = 0; i < 4; ++i)
        af[i] = *(const bf16x8*)&As[p * 4096 + (wm * 64 + i * 16 + ln) * 32 + quad * 8];
#pragma unroll
      for (int j = 0; j < 4; ++j)
        bfr[j] = *(const bf16x8*)&Bs[p * 4096 + (wn * 64 + j * 16 + ln) * 32 + quad * 8];
#pragma unroll
      for (int i = 0; i < 4; ++i)
#pragma unroll
        for (int j = 0; j < 4; ++j)
          acc[i][j] = __builtin_amdgcn_mfma_f32_16x16x32_bf16(af[i], bfr[j], acc[i][j], 0, 0, 0);
    }
  }

  float biasj[4];
#pragma unroll
  for (int j = 0; j < 4; ++j) biasj[j] = bias[n0 + wn * 64 + j * 16 + ln];

  if (z != 2) {
#pragma unroll
    for (int i = 0; i < 4; ++i)
#pragma unroll
      for (int j = 0; j < 4; ++j)
#pragma unroll
        for (int r = 0; r < 4; ++r) {
          int m = m0 + wm * 64 + i * 16 + quad * 4 + r;
          int n = n0 + wn * 64 + j * 16 + ln;
          int b_ = m >> 11, s = m & 2047;
          int h = n >> 6, d = n & 63;
          outb[(((size_t)b_ * Hh + h) * Ss + s) * HD + d] = f2bf((acc[i][j][r] + biasj[j]) * osc);
        }
  } else {
    for (int half = 0; half < 2; ++half) {
      __syncthreads();
      if (wm == half) {
#pragma unroll
        for (int i = 0; i < 4; ++i)
#pragma unroll
          for (int j = 0; j < 4; ++j)
#pragma unroll
            for (int r = 0; r < 4; ++r) {
              int mr = i * 16 + quad * 4 + r;
              int nc = wn * 64 + j * 16 + ln;
              SMEM[nc * 72 + mr] = f2bf(acc[i][j][r] + biasj[j]);
            }
      }
      __syncthreads();
      int nr = t >> 1;
      int n = n0 + nr;
      int h = n >> 6, d = n & 63;
      int mbase = m0 + half * 64 + (t & 1) * 32;
      int b_ = mbase >> 11;
#pragma unroll
      for (int q = 0; q < 4; ++q) {
        int s = (mbase & 2047) + q * 8;
        us8 vdat = *(const us8*)&SMEM[nr * 72 + (t & 1) * 32 + q * 8];
        *(us8*)&outb[(((size_t)b_ * Hh + h) * HD + d) * Ss + s] = vdat;
      }
    }
  }
}

// Flash attention, causal, S^T = K Q^T, max-free exp2 softmax.
// grid = 1024 (64 bh x 16 pairs {31-p, p}); 64-row q-tile per block;
// KT=128 per stage (two 64-k subtiles) -> one barrier pair per 36 MFMA.
__global__ __launch_bounds__(256) void flash_attn(const unsigned short* __restrict__ qkv,
                                                  float* __restrict__ out) {
  const int id = blockIdx.x;
  const int bh = id & 63;
  const int p = id >> 6;             // 0..15
  const int b_ = bh >> 4, h = bh & 15;

  const unsigned short* qb  = qkv + (size_t)bh * (Ss * HD);
  const unsigned short* kb  = qkv + (size_t)(64 + bh) * (Ss * HD);
  const unsigned short* vtb = qkv + (size_t)(128 + bh) * (Ss * HD);  // [d][s]

  __shared__ __bf16 Ks[8192];          // two 64x64 subtiles, swizzled slots
  __shared__ __bf16 Vt[8192];          // two [d][kk] subtiles, same swizzle
  __shared__ __bf16 Ps[4][16][72];     // wave-private P [qrow][kk]

  const int t = threadIdx.x;
  const int wave = t >> 6, lane = t & 63, quad = lane >> 4, ln = lane & 15;

  const int r0 = t >> 3;
  const int c0 = ((t & 7) ^ (r0 & 7)) * 8;
  const int koff0 = r0 * HD + c0;
  const int koff1 = koff0 + 32 * HD;
  const int voff0 = r0 * Ss + c0;
  const int voff1 = voff0 + 32 * Ss;
  __bf16* Kl0 = &Ks[t * 8];  __bf16* Kl1 = &Ks[2048 + t * 8];
  __bf16* Vl0 = &Vt[t * 8];  __bf16* Vl1 = &Vt[2048 + t * 8];

  int kslot[4][2];
#pragma unroll
  for (int g = 0; g < 4; ++g)
#pragma unroll
    for (int ks = 0; ks < 2; ++ks)
      kslot[g][ks] = ((g * 16 + ln) * 8 + ((ks * 4 + quad) ^ (ln & 7))) * 8;

  bf16x8 onef;
#pragma unroll
  for (int j = 0; j < 8; ++j) onef[j] = (__bf16)1.0f;

  const int qts[2] = { 31 - p, p };

  for (int ph = 0; ph < 2; ++ph) {
    const int qt = qts[ph];
    const int q0 = qt * 64;
    const int qrow = q0 + wave * 16 + ln;
    const int nst = (qt + 2) >> 1;     // 128-wide stages

    bf16x8 qf[2];
#pragma unroll
    for (int ks = 0; ks < 2; ++ks)
      qf[ks] = *(const bf16x8*)(qb + (size_t)qrow * HD + ks * 32 + quad * 8);

    f32x4 o[4] = {};
    f32x4 l4 = {};

    for (int st = 0; st < nst; ++st) {
      const int k2 = 2 * st;                       // first 64-subtile index
      const unsigned short* kbt = kb + (size_t)k2 * (64 * HD);
      const unsigned short* vbt = vtb + k2 * 64;
      __syncthreads();
      gl_lds16(kbt + koff0,           Kl0);
      gl_lds16(kbt + koff1,           Kl1);
      gl_lds16(kbt + 64 * HD + koff0, Kl0 + 4096);
      gl_lds16(kbt + 64 * HD + koff1, Kl1 + 4096);
      gl_lds16(vbt + voff0,           Vl0);
      gl_lds16(vbt + voff1,           Vl1);
      gl_lds16(vbt + 64 + voff0,      Vl0 + 4096);
      gl_lds16(vbt + 64 + voff1,      Vl1 + 4096);
      __syncthreads();

#pragma unroll
      for (int sub = 0; sub < 2; ++sub) {
        const int kt = k2 + sub;
        if (kt > qt) continue;                     // fully-masked subtile
        const int sofs = sub * 4096;

        // S^T = K Q^T
        f32x4 s_acc[4] = {};
#pragma unroll
        for (int g = 0; g < 4; ++g)
#pragma unroll
          for (int ks = 0; ks < 2; ++ks) {
            bf16x8 kf = *(const bf16x8*)&Ks[sofs + kslot[g][ks]];
            s_acc[g] = __builtin_amdgcn_mfma_f32_16x16x32_bf16(kf, qf[ks], s_acc[g], 0, 0, 0);
          }

        if (kt == qt) {                            // diagonal tile
          const int k0 = kt * 64;
#pragma unroll
          for (int g = 0; g < 4; ++g)
#pragma unroll
            for (int r = 0; r < 4; ++r) {
              int kcol = k0 + g * 16 + quad * 4 + r;
              if (kcol > qrow) s_acc[g][r] = -__builtin_inff();
            }
        }

        // p = exp2(s) (max-free), pack -> Ps
#pragma unroll
        for (int g = 0; g < 4; ++g) {
          bf16x4 pk = { (__bf16)EXP2(s_acc[g][0]), (__bf16)EXP2(s_acc[g][1]),
                        (__bf16)EXP2(s_acc[g][2]), (__bf16)EXP2(s_acc[g][3]) };
          *(bf16x4*)&Ps[wave][ln][g * 16 + quad * 4] = pk;
        }
        bf16x8 pf[2];
#pragma unroll
        for (int ks = 0; ks < 2; ++ks)
          pf[ks] = *(const bf16x8*)&Ps[wave][ln][ks * 32 + quad * 8];

        // l += P @ ones (row sums in O-row layout)
        l4 = __builtin_amdgcn_mfma_f32_16x16x32_bf16(pf[0], onef, l4, 0, 0, 0);
        l4 = __builtin_amdgcn_mfma_f32_16x16x32_bf16(pf[1], onef, l4, 0, 0, 0);

        // O += P V
#pragma unroll
        for (int g = 0; g < 4; ++g)
#pragma unroll
          for (int ks = 0; ks < 2; ++ks) {
            bf16x8 vf = *(const bf16x8*)&Vt[sofs + kslot[g][ks]];
            o[g] = __builtin_amdgcn_mfma_f32_16x16x32_bf16(pf[ks], vf, o[g], 0, 0, 0);
          }
      }
    }

    float linv[4];
#pragma unroll
    for (int r = 0; r < 4; ++r) linv[r] = 1.0f / l4[r];
#pragma unroll
    for (int g = 0; g < 4; ++g)
#pragma unroll
      for (int r = 0; r < 4; ++r) {
        int orow = q0 + wave * 16 + quad * 4 + r;
        out[((size_t)b_ * Ss + orow) * Ee + h * HD + g * 16 + ln] = o[g][r] * linv[r];
      }
    __syncthreads();   // protect LDS before next phase restages
  }
}

extern "C" void kernel_launch(void* const* d_in, const int* in_sizes, int n_in,
                              void* d_out, int out_size, void* d_ws, size_t ws_size,
                              hipStream_t stream) {
  const float* x  = (const float*)d_in[0];
  const float* Wq = (const float*)d_in[1];
  const float* bq = (const float*)d_in[2];
  const float* Wk = (const float*)d_in[3];
  const float* bk = (const float*)d_in[4];
  const float* Wv = (const float*)d_in[5];
  const float* bv = (const float*)d_in[6];
  float* out = (float*)d_out;

  unsigned short* ws  = (unsigned short*)d_ws;
  unsigned short* xb  = ws;                                   // 8388608
  unsigned short* wb  = ws + 8388608;                         // 3 * 1048576
  unsigned short* qkv = ws + 8388608 + 3 * 1048576;           // 3 * 8388608

  cvt_all<<<11264, 256, 0, stream>>>(x, Wq, Wk, Wv, xb, wb);
  qkv_gemm<<<dim3(64, 8, 3), 256, 0, stream>>>(xb, wb, bq, bk, bv, qkv);
  flash_attn<<<1024, 256, 0, stream>>>(qkv, out);
}